// Round 4
// baseline (173.624 us; speedup 1.0000x reference)
//
#include <hip/hip_runtime.h>
#include <hip/hip_bf16.h>

// Contrastive loss: N=4096, V=2, D=256.  M=8192 view-major rows.
// loss = mean_i [ log sum_{j!=i} exp(l_ij/T) - l_{i,pos}/T ],  l = norm(A)@norm(B)^T.
// Round 4: A fragments register-resident (K=256 fits: 32 short8/wave), B-only LDS
// double-buffer with counted vmcnt(4), setprio around MFMA, fused final reduction
// (last-block pattern) -> 2 dispatches total.

#define N_SAMP 4096
#define DIM    256
#define M_ROWS 8192
#define TEMP   0.07f

using short8 = __attribute__((ext_vector_type(8))) short;
using f32x4  = __attribute__((ext_vector_type(4))) float;

#define GLDS(g, l) __builtin_amdgcn_global_load_lds( \
    (const __attribute__((address_space(1))) void*)(g), \
    (__attribute__((address_space(3))) void*)(l), 16, 0, 0)

// ---------------------------------------------------------------------------
// Normalize rows (view-major) -> bf16; zero S / PosSum / cnt.
// ---------------------------------------------------------------------------
__global__ __launch_bounds__(256) void norm_kernel(
    const float* __restrict__ A, const float* __restrict__ B,
    unsigned short* __restrict__ Ah, unsigned short* __restrict__ Bh,
    float* __restrict__ S, float* __restrict__ PosSum, int* __restrict__ cnt)
{
  int tid = threadIdx.x;
  if (blockIdx.x < 8)
    ((float4*)S)[blockIdx.x * 256 + tid] = (float4){0.f, 0.f, 0.f, 0.f};
  if (blockIdx.x == 8 && tid == 0) { PosSum[0] = 0.f; cnt[0] = 0; }

  int wave = tid >> 6, lane = tid & 63;
  int gw   = blockIdx.x * 4 + wave;          // 0 .. 2*M-1
  const float* src; unsigned short* dst; int m;
  if (gw < M_ROWS) { src = A; dst = Ah; m = gw; }
  else             { src = B; dst = Bh; m = gw - M_ROWS; }
  int n = m & (N_SAMP - 1);
  int v = m >> 12;
  const float4* in = (const float4*)(src + (size_t)(n * 2 + v) * DIM);
  float4 x = in[lane];
  float ss = x.x*x.x + x.y*x.y + x.z*x.z + x.w*x.w;
  #pragma unroll
  for (int d = 1; d < 64; d <<= 1) ss += __shfl_xor(ss, d);
  float scale = 1.0f / fmaxf(sqrtf(ss), 1e-12f);
  float vals[4] = {x.x*scale, x.y*scale, x.z*scale, x.w*scale};
  ushort4 o;
  unsigned short* op = (unsigned short*)&o;
  #pragma unroll
  for (int k = 0; k < 4; ++k) {              // f32 -> bf16 RNE
    unsigned int u = __float_as_uint(vals[k]);
    u += 0x7fffu + ((u >> 16) & 1u);
    op[k] = (unsigned short)(u >> 16);
  }
  *(ushort4*)(dst + (size_t)m * DIM + lane * 4) = o;
}

// ---------------------------------------------------------------------------
// GEMM + fused LSE-sum epilogue + fused final reduction (last block).
// Block = 128 rows x 2048 cols, 512 thr (8 waves 2x4), 1 block/CU.
// ---------------------------------------------------------------------------
__global__ __launch_bounds__(512, 2) void gemm_lse_kernel(
    const unsigned short* __restrict__ Ah, const unsigned short* __restrict__ Bh,
    float* __restrict__ S, float* __restrict__ PosSum, int* __restrict__ cnt,
    float* __restrict__ out)
{
  __shared__ alignas(16) char lds[65536 + 2 * 32768];   // As 64KB | Bs0 | Bs1
  __shared__ float redbuf[8];
  __shared__ int lastFlag;
  char* As  = lds;
  char* Bs0 = lds + 65536;
  char* Bs1 = lds + 65536 + 32768;

  int tid  = threadIdx.x;
  int lane = tid & 63;
  int w    = tid >> 6;
  int wrow = w >> 2, wcol = w & 3;           // 2x4 wave grid, 64x64 each
  int row0 = blockIdx.y * 128;
  int col0 = blockIdx.x * 2048;

  // ---- prologue: stage full A tile to LDS (swizzled source, linear dest).
  #pragma unroll
  for (int s = 0; s < 8; ++s) {
    int f = s * 512 + tid;
    int r = f >> 5, cd = f & 31;             // row 0..127, 16B chunk 0..31
    int cs = cd ^ (r & 7);
    GLDS((const char*)Ah + (size_t)(row0 + r) * 512 + cs * 16, As + f * 16);
  }
  __syncthreads();                           // drains vm + lgkm

  // ---- A fragments -> registers, once.  a[ck][f], ck = ks*2+kk (K chunk of 32).
  short8 a[8][4];
  #pragma unroll
  for (int ck = 0; ck < 8; ++ck) {
    int ca = ck * 4 + (lane >> 4);
    #pragma unroll
    for (int f = 0; f < 4; ++f) {
      int ar = wrow * 64 + f * 16 + (lane & 15);
      a[ck][f] = *(const short8*)(As + ar * 512 + ((ca ^ (ar & 7)) * 16));
    }
  }

  // B stage: coltile ctn, kstep ksn -> 4 glds x 16B/thread (32KB).
  auto stageB = [&](int ctn, int ksn, char* Bbuf) {
    const char* base = (const char*)Bh + (size_t)(col0 + ctn * 256) * 512 + ksn * 128;
    #pragma unroll
    for (int s = 0; s < 4; ++s) {
      int f = s * 512 + tid;
      int r = f >> 3, cd = f & 7;            // col-row 0..255, chunk 0..7
      int cs = cd ^ (r & 7);
      GLDS(base + (size_t)r * 512 + cs * 16, Bbuf + f * 16);
    }
  };
  stageB(0, 0, Bs0);

  f32x4 acc[4][4];
  float ssum[4][4];
  #pragma unroll
  for (int i = 0; i < 4; ++i)
    #pragma unroll
    for (int r = 0; r < 4; ++r) ssum[i][r] = 0.f;
  float psum = 0.f;                          // positives accumulator

  const float KE = (float)(1.4426950408889634 / 0.07);  // log2(e)/T

  #pragma unroll 1
  for (int ct = 0; ct < 8; ++ct) {
    #pragma unroll
    for (int ks = 0; ks < 4; ++ks) {         // static ks -> static a[] indices
      char* Bcur = (ks & 1) ? Bs1 : Bs0;     // t = ct*4+ks, t&1 == ks&1
      char* Bnxt = (ks & 1) ? Bs0 : Bs1;
      if (ks < 3) {
        stageB(ct, ks + 1, Bnxt);
        asm volatile("s_waitcnt vmcnt(4)" ::: "memory");
      } else if (ct < 7) {
        stageB(ct + 1, 0, Bnxt);
        asm volatile("s_waitcnt vmcnt(4)" ::: "memory");
      } else {
        asm volatile("s_waitcnt vmcnt(0)" ::: "memory");
      }
      __builtin_amdgcn_s_barrier();
      __builtin_amdgcn_sched_barrier(0);

      if (ks == 0) {
        #pragma unroll
        for (int i = 0; i < 4; ++i)
          #pragma unroll
          for (int j = 0; j < 4; ++j)
            acc[i][j] = (f32x4){0.f, 0.f, 0.f, 0.f};
      }

      __builtin_amdgcn_s_setprio(1);
      #pragma unroll
      for (int kk = 0; kk < 2; ++kk) {
        short8 b[4];
        int cb = kk * 4 + (lane >> 4);
        #pragma unroll
        for (int f = 0; f < 4; ++f) {
          int br = wcol * 64 + f * 16 + (lane & 15);
          b[f] = *(const short8*)(Bcur + br * 128 + ((cb ^ (br & 7)) * 16));
        }
        #pragma unroll
        for (int i = 0; i < 4; ++i)
          #pragma unroll
          for (int j = 0; j < 4; ++j)
            acc[i][j] = __builtin_amdgcn_mfma_f32_16x16x32_bf16(a[ks * 2 + kk][i], b[j], acc[i][j], 0, 0, 0);
      }
      __builtin_amdgcn_s_setprio(0);

      if (ks == 3) {                         // coltile done: fused epilogue
        #pragma unroll
        for (int i = 0; i < 4; ++i) {
          #pragma unroll
          for (int j = 0; j < 4; ++j) {
            int gj = col0 + ct * 256 + wcol * 64 + j * 16 + (lane & 15);
            #pragma unroll
            for (int r = 0; r < 4; ++r) {
              int gi = row0 + wrow * 64 + i * 16 + (lane >> 4) * 4 + r;
              float l = acc[i][j][r];
              float e = exp2f(l * KE);
              if (((gi ^ gj) & (N_SAMP - 1)) == 0) {
                if (gi == gj) e = 0.f;       // diagonal excluded
                else psum += l;              // the one positive for row gi
              }
              ssum[i][r] += e;
            }
          }
        }
      }
      __builtin_amdgcn_s_barrier();
      __builtin_amdgcn_sched_barrier(0);
    }
  }

  // ---- per-row partial sums -> S (one atomic per row per wave).
  #pragma unroll
  for (int i = 0; i < 4; ++i) {
    #pragma unroll
    for (int r = 0; r < 4; ++r) {
      float v = ssum[i][r];
      v += __shfl_xor(v, 1);
      v += __shfl_xor(v, 2);
      v += __shfl_xor(v, 4);
      v += __shfl_xor(v, 8);
      if ((lane & 15) == 0) {
        int gi = row0 + wrow * 64 + i * 16 + (lane >> 4) * 4 + r;
        atomicAdd(&S[gi], v);
      }
    }
  }
  // ---- positives: block-reduce then one atomic.
  float pv = psum;
  #pragma unroll
  for (int d = 1; d < 64; d <<= 1) pv += __shfl_xor(pv, d);
  if (lane == 0) redbuf[w] = pv;
  __syncthreads();
  if (tid == 0) {
    float t = 0.f;
    #pragma unroll
    for (int k = 0; k < 8; ++k) t += redbuf[k];
    atomicAdd(PosSum, t);
  }

  // ---- completion counter; last block computes the loss.
  __threadfence();
  if (tid == 0) lastFlag = (atomicAdd(cnt, 1) == 255);
  __syncthreads();
  if (lastFlag) {
    __threadfence();
    float part = 0.f;
    for (int i = tid; i < M_ROWS; i += 512)
      part += logf(atomicAdd(&S[i], 0.0f));  // coherent read
    #pragma unroll
    for (int d = 1; d < 64; d <<= 1) part += __shfl_xor(part, d);
    __syncthreads();                         // redbuf reuse
    if (lane == 0) redbuf[w] = part;
    __syncthreads();
    if (tid == 0) {
      float sl = 0.f;
      #pragma unroll
      for (int k = 0; k < 8; ++k) sl += redbuf[k];
      float ps = atomicAdd(PosSum, 0.0f);    // coherent read
      out[0] = sl / (float)M_ROWS - ps / ((float)M_ROWS * TEMP);
    }
  }
}

extern "C" void kernel_launch(void* const* d_in, const int* in_sizes, int n_in,
                              void* d_out, int out_size, void* d_ws, size_t ws_size,
                              hipStream_t stream)
{
  const float* A = (const float*)d_in[0];
  const float* B = (const float*)d_in[1];
  char* ws = (char*)d_ws;
  unsigned short* Ah = (unsigned short*)ws;                                  // 4 MB
  unsigned short* Bh = (unsigned short*)(ws + (size_t)M_ROWS * DIM * 2);     // 4 MB
  float* S      = (float*)(ws + 2 * (size_t)M_ROWS * DIM * 2);               // 32 KB
  float* PosSum = S + M_ROWS;
  int*   cnt    = (int*)(PosSum + 1);

  norm_kernel<<<dim3(2 * M_ROWS / 4), 256, 0, stream>>>(A, B, Ah, Bh, S, PosSum, cnt);
  gemm_lse_kernel<<<dim3(4, 64), 512, 0, stream>>>(Ah, Bh, S, PosSum, cnt, (float*)d_out);
}